// Round 11
// baseline (221.983 us; speedup 1.0000x reference)
//
#include <hip/hip_runtime.h>
#include <hip/hip_bf16.h>
#include <cmath>
#include <cstring>

#define B_SZ   512
#define SLEN   1000
#define DD     16
#define HID    256
#define WIN    64
#define PAIRS  120
#define LSIG   136
#define NWIN   20
#define MAXST  21
#define K1P    416     // layer-1 K padded to x32
#define W1FN   (13 * 16 * 64 * 8)   // 106496 elems
#define WFN    (8 * 16 * 64 * 8)    // 65536 elems (W2/W3/Wl)
#define PSTEP  21      // partial buffer step slots (nsteps <= 20)

using short8  = __attribute__((ext_vector_type(8))) short;
using short4v = __attribute__((ext_vector_type(4))) short;
using half8   = __attribute__((ext_vector_type(8))) _Float16;
using f32x4   = __attribute__((ext_vector_type(4))) float;

struct SchedArgs { short snapk[SLEN - 1]; };
struct CombPArgs { unsigned char winofm[WIN]; unsigned char zl[WIN]; unsigned char sstep[WIN]; };
struct ChainArgs { int nsteps; unsigned char kU[32]; };
struct FuseArgs  { unsigned char sidx[WIN]; };

__device__ __forceinline__ unsigned short f2h(float x) {
  _Float16 h = (_Float16)x;
  return __builtin_bit_cast(unsigned short, h);
}
__device__ __forceinline__ float ftanh(float x) {   // clamped; |err|~1e-6
  float t = fminf(fmaxf(2.f * x, -30.f), 30.f);
  float e = __expf(t);
  return (e - 1.f) / (e + 1.f);
}

// ---------------------------------------------------------------- prep: win scan + weight frag convert
// grid (NWIN+3, B_SZ) x 128. Blocks w<NWIN: per-window Levy scan. Else: convert
// W1/W2/W3/Wl -> fp16 MFMA B-frag layout:
//   Wf[(kk*16+nsub)*64+lane][j] = W[nsub*16+(lane&15)][kk*32+(lane>>4)*8+j]
__global__ __launch_bounds__(128) void prep_kernel(
    const float* __restrict__ z,
    const float* __restrict__ W1, const float* __restrict__ W2,
    const float* __restrict__ W3, const float* __restrict__ Wl,
    float* __restrict__ logsig, float* __restrict__ dxwin,
    unsigned short* __restrict__ W1f, unsigned short* __restrict__ W2f,
    unsigned short* __restrict__ W3f, unsigned short* __restrict__ Wlf,
    SchedArgs A)
{
  const int w = blockIdx.x, b = blockIdx.y, tid = threadIdx.x;
  if (w >= NWIN) {                                   // ---- weight conversion
    const int slot = ((w - NWIN) * B_SZ + b) * 128 + tid;   // 196608 slots
    for (int e = slot; e < W1FN + 3 * WFN; e += 3 * B_SZ * 128) {
      if (e < W1FN) {
        int f = e;
        int j = f & 7, l15 = (f >> 3) & 15, lq = (f >> 7) & 3, nsub = (f >> 9) & 15, kk = f >> 13;
        int row = nsub * 16 + l15, col = kk * 32 + lq * 8 + j;
        float v = (col < HID + LSIG) ? W1[(size_t)row * (HID + LSIG) + col] : 0.f;
        W1f[f] = f2h(v);
      } else {
        int e2 = e - W1FN;
        int which = e2 >> 16, f = e2 & 65535;
        int j = f & 7, l15 = (f >> 3) & 15, lq = (f >> 7) & 3, nsub = (f >> 9) & 15, kk = (f >> 13) & 7;
        int row = nsub * 16 + l15, col = kk * 32 + lq * 8 + j;
        const float* src = which == 0 ? W2 : which == 1 ? W3 : Wl;
        unsigned short* dst = which == 0 ? W2f : which == 1 ? W3f : Wlf;
        dst[f] = f2h(src[(size_t)row * HID + col]);
      }
    }
    return;
  }
  // ---- per-window Levy scan (dtsqrt inlined)
  __shared__ float zs[50][16];
  const int ns = (w == NWIN - 1) ? 49 : 50;
  const float* src = z + ((size_t)b * SLEN + 50 * w + 1) * DD;
  const double s999 = 1.0 / (double)(SLEN - 1);
  for (int c = tid; c < ns * 4; c += 128) {
    float4 v = ((const float4*)src)[c];
    int t = 50 * w + (c >> 2);
    double a = (t + 1 == SLEN - 1) ? 1.0 : (double)(t + 1) * s999;
    float s = sqrtf((float)(a - (double)t * s999));
    v.x *= s; v.y *= s; v.z *= s; v.w *= s;
    ((float4*)&zs[0][0])[c] = v;
  }
  int pi = 0, pj = 0;
  if (tid < PAIRS) { int rem = tid, i = 0; while (rem >= DD - 1 - i) { rem -= DD - 1 - i; ++i; } pi = i; pj = i + 1 + rem; }
  __syncthreads();
  float Yi = 0.f, Yj = 0.f, LL = 0.f, Yd = 0.f;
  const int base_t = 50 * w;
  for (int u = 0; u < ns; ++u) {
    const float di = zs[u][pi], dj = zs[u][pj];
    LL = fmaf(Yi, dj, LL); LL = fmaf(-Yj, di, LL);
    Yi += di; Yj += dj;
    if (tid < DD) Yd += zs[u][tid];
    const int m = A.snapk[base_t + u];
    if (m) {
      float* dst = logsig + ((size_t)b * WIN + m) * LSIG;
      if (tid < DD)    dst[tid]      = Yd;
      if (tid < PAIRS) dst[DD + tid] = LL;
    }
  }
  if (tid < DD) dxwin[((size_t)b * NWIN + w) * DD + tid] = Yd;
}

// ---------------------------------------------------------------- combine + logsig partial (merged)
// grid (WIN, 32) x 256. Block (k, g): finalize logsig rows for 16 batches
// (b = 16g..16g+15) at window k (level-1 add + Levy adjust), then -- if k is
// an update step (sstep[k]!=255) -- compute the chain's L1 partial
// partial[g][s][row][col] = (W1s . logsig)[row][col] + b1[col] straight from
// LDS with swapped-operand MFMA (D[feature][batch]: lane&15 = batch row, each
// lane holds 4 consecutive out-cols -> row-major float4 store).
// NOTE (r9 lesson): do NOT merge this lean kernel with the register-fat
// chain -- one kernel = one register allocation; producers inherit the fat
// footprint and occupancy collapses (measured 5x regression).
__global__ __launch_bounds__(256) void combp_kernel(
    float* __restrict__ logsig, const float* __restrict__ dxwin,
    const unsigned short* __restrict__ W1f, const float* __restrict__ b1,
    float* __restrict__ partial, CombPArgs A)
{
  __shared__ float Xs[16][16], Yt[16][16];
  __shared__ __align__(16) unsigned short As[20 * 16 * 8];   // 160 cols, chunk-8
  const int k = blockIdx.x, g = blockIdx.y, tid = threadIdx.x;
  const int w = A.winofm[k], zl = A.zl[k], ss = A.sstep[k];
  for (int c = tid; c < 3 * 16 * 8; c += 256) As[17 * 16 * 8 + c] = 0;  // zero pad cols 136..159
  {                                                   // ---- level-1 (tid = bi*16+col)
    const int bi = tid >> 4, col = tid & 15;
    const size_t b = (size_t)(g * 16 + bi);
    float acc = 0.f;
    for (int ww = 0; ww < w; ++ww) acc += dxwin[(b * NWIN + ww) * DD + col];
    float y = (k == 0) ? 0.f : logsig[(b * WIN + k) * LSIG + col];
    float fin = (k == 0) ? 0.f : acc + y;
    Xs[bi][col] = acc; Yt[bi][col] = y;
    logsig[(b * WIN + k) * LSIG + col] = fin;
    As[((col >> 3) * 16 + bi) * 8 + (col & 7)] = f2h(fin);
  }
  __syncthreads();
  for (int idx = tid; idx < 16 * PAIRS; idx += 256) {  // ---- Levy pairs
    const int bi = idx / PAIRS, p = idx - bi * PAIRS;
    int rem = p, i = 0; while (rem >= DD - 1 - i) { rem -= DD - 1 - i; ++i; }
    const int pi = i, pj = i + 1 + rem;
    const size_t b = (size_t)(g * 16 + bi);
    float ll = (k == 0) ? 0.f : logsig[(b * WIN + k) * LSIG + DD + p];
    float fin = (k == 0 || zl) ? 0.f
              : 0.5f * (ll + Xs[bi][pi] * Yt[bi][pj] - Xs[bi][pj] * Yt[bi][pi]);
    logsig[(b * WIN + k) * LSIG + DD + p] = fin;
    const int c = DD + p;
    As[((c >> 3) * 16 + bi) * 8 + (c & 7)] = f2h(fin);
  }
  if (ss == 255) return;                               // uniform across block
  __syncthreads();
  const int lane = tid & 63, wv = tid >> 6;
  const int l15 = lane & 15, lq = lane >> 4;
  f32x4 acc4[4] = {{0,0,0,0},{0,0,0,0},{0,0,0,0},{0,0,0,0}};
#pragma unroll
  for (int kt = 0; kt < 5; ++kt) {
    half8 af = *(const half8*)&As[((kt * 4 + lq) * 16 + l15) * 8];
#pragma unroll
    for (int t = 0; t < 4; ++t) {
      half8 bfW = *(const half8*)(W1f + ((size_t)((8 + kt) * 16 + wv * 4 + t) * 64 + lane) * 8);
      acc4[t] = __builtin_amdgcn_mfma_f32_16x16x32_f16(bfW, af, acc4[t], 0, 0, 0);
    }
  }
#pragma unroll
  for (int t = 0; t < 4; ++t) {
    const int col0 = wv * 64 + t * 16 + lq * 4;
    f32x4 bb = *(const f32x4*)(b1 + col0);
    f32x4 r = acc4[t] + bb;
    *(f32x4*)&partial[(((size_t)g * PSTEP + ss) * 16 + l15) * HID + col0] = r;
  }
}

// ---------------------------------------------------------------- sequential state chain (fp16 MFMA)
// = r6 (proven 46.5us, 5x reproduced). 32 blocks x 512 thr (8 waves, 2/SIMD).
// Wave w owns cols [32w,32w+32). All weights (48 half8 frags) resident in the
// unified VGPR/AGPR file. SWAPPED-OPERAND MFMA: D cols = batch (lane&15),
// each lane holds 4 consecutive feature cols -> packed b64 LDS epilogues +
// 8B global state stores (deferred one step). 3 barriers/step.
__global__ __attribute__((amdgpu_flat_work_group_size(512, 512)))
__attribute__((amdgpu_waves_per_eu(2, 2)))
void chain_kernel(
    const float* __restrict__ partial,
    const unsigned short* __restrict__ W1f, const unsigned short* __restrict__ W2f,
    const unsigned short* __restrict__ W3f,
    const float* __restrict__ b2, const float* __restrict__ b3,
    unsigned short* __restrict__ statesb, ChainArgs A)
{
  __shared__ __align__(16) unsigned short A0s[32 * 16 * 8];   // 8 KB (h, chunk-8)
  __shared__ __align__(16) unsigned short A1s[32 * 16 * 8];   // 8 KB
  __shared__ __align__(16) unsigned short A2s[32 * 16 * 8];   // 8 KB
  const int tid = threadIdx.x, g = blockIdx.x;
  const int lane = tid & 63, w = tid >> 6;
  const int l15 = lane & 15, lq = lane >> 4;

  for (int c = tid; c < 32 * 16 * 8; c += 512) A0s[c] = 0;
  for (int c = tid; c < 16 * HID / 4; c += 512) {             // state 0 = zeros (8B packed)
    int r = c >> 6, col = (c & 63) * 4;
    *(short4v*)&statesb[((size_t)(g * 16 + r) * MAXST + 0) * HID + col] = (short4v){0, 0, 0, 0};
  }

  // ---- all weight frags -> registers (once, resident across all steps)
  half8 W1r[16], W2r[16], W3r[16];
#pragma unroll
  for (int kk = 0; kk < 8; ++kk)
#pragma unroll
    for (int nt = 0; nt < 2; ++nt) {
      W1r[kk * 2 + nt] = *(const half8*)(W1f + ((size_t)(kk * 16 + w * 2 + nt) * 64 + lane) * 8);
      W2r[kk * 2 + nt] = *(const half8*)(W2f + ((size_t)(kk * 16 + w * 2 + nt) * 64 + lane) * 8);
      W3r[kk * 2 + nt] = *(const half8*)(W3f + ((size_t)(kk * 16 + w * 2 + nt) * 64 + lane) * 8);
    }

  // per-lane column base (4 consecutive cols) for each n-tile
  int colb[2];
  f32x4 bias2v[2], bias3v[2];
#pragma unroll
  for (int nt = 0; nt < 2; ++nt) {
    colb[nt] = w * 32 + nt * 16 + lq * 4;
    bias2v[nt] = *(const f32x4*)(b2 + colb[nt]);
    bias3v[nt] = *(const f32x4*)(b3 + colb[nt]);
  }

  // partial prefetch plumbing (row-major [step][row16][256], float4/lane)
  const float* pbase = partial + (size_t)g * PSTEP * 16 * HID;
  int poff[2];
#pragma unroll
  for (int nt = 0; nt < 2; ++nt) poff[nt] = l15 * HID + colb[nt];
  f32x4 pf[2];
  pf[0] = *(const f32x4*)(pbase + poff[0]);
  pf[1] = *(const f32x4*)(pbase + poff[1]);

  short4v hv4[2];                                     // deferred packed state stores
  __syncthreads();                                    // A0s zeros visible

  for (int m = 0; m < A.nsteps; ++m) {
    if (m > 0) {                                      // store state m (from step m-1), 8B packed
#pragma unroll
      for (int nt = 0; nt < 2; ++nt)
        *(short4v*)&statesb[((size_t)(g * 16 + l15) * MAXST + m) * HID + colb[nt]] = hv4[nt];
    }
    // ---- L1: K=256 (h part), acc seeded from partial (has W1s.logsig + b1)
    {
      f32x4 acc[2][2];
      acc[0][0] = pf[0]; acc[0][1] = pf[1];
      acc[1][0] = (f32x4){0.f,0.f,0.f,0.f}; acc[1][1] = (f32x4){0.f,0.f,0.f,0.f};
      if (m + 1 < A.nsteps) {                         // prefetch next step's partial
        const float* pp = pbase + (size_t)(m + 1) * 16 * HID;
        pf[0] = *(const f32x4*)(pp + poff[0]);
        pf[1] = *(const f32x4*)(pp + poff[1]);
      }
#pragma unroll
      for (int kk = 0; kk < 8; ++kk) {
        half8 af = *(const half8*)&A0s[((kk * 4 + lq) * 16 + l15) * 8];
        acc[kk & 1][0] = __builtin_amdgcn_mfma_f32_16x16x32_f16(W1r[kk * 2    ], af, acc[kk & 1][0], 0, 0, 0);
        acc[kk & 1][1] = __builtin_amdgcn_mfma_f32_16x16x32_f16(W1r[kk * 2 + 1], af, acc[kk & 1][1], 0, 0, 0);
      }
#pragma unroll
      for (int nt = 0; nt < 2; ++nt) {
        f32x4 s = acc[0][nt] + acc[1][nt];
        short4v h4;
#pragma unroll
        for (int r4 = 0; r4 < 4; ++r4) h4[r4] = (short)f2h(fmaxf(s[r4], 0.f));
        *(short4v*)&A1s[((colb[nt] >> 3) * 16 + l15) * 8 + (colb[nt] & 7)] = h4;
      }
    }
    __syncthreads();
    // ---- L2: K=256, W2 from registers
    {
      f32x4 acc[2][2] = {{{0.f,0.f,0.f,0.f},{0.f,0.f,0.f,0.f}},{{0.f,0.f,0.f,0.f},{0.f,0.f,0.f,0.f}}};
#pragma unroll
      for (int kk = 0; kk < 8; ++kk) {
        half8 af = *(const half8*)&A1s[((kk * 4 + lq) * 16 + l15) * 8];
        acc[kk & 1][0] = __builtin_amdgcn_mfma_f32_16x16x32_f16(W2r[kk * 2    ], af, acc[kk & 1][0], 0, 0, 0);
        acc[kk & 1][1] = __builtin_amdgcn_mfma_f32_16x16x32_f16(W2r[kk * 2 + 1], af, acc[kk & 1][1], 0, 0, 0);
      }
#pragma unroll
      for (int nt = 0; nt < 2; ++nt) {
        f32x4 s = acc[0][nt] + acc[1][nt] + bias2v[nt];
        short4v h4;
#pragma unroll
        for (int r4 = 0; r4 < 4; ++r4) h4[r4] = (short)f2h(fmaxf(s[r4], 0.f));
        *(short4v*)&A2s[((colb[nt] >> 3) * 16 + l15) * 8 + (colb[nt] & 7)] = h4;
      }
    }
    __syncthreads();
    // ---- L3: K=256, W3 from registers; fast tanh -> A0 state; global store deferred
    {
      f32x4 acc[2][2] = {{{0.f,0.f,0.f,0.f},{0.f,0.f,0.f,0.f}},{{0.f,0.f,0.f,0.f},{0.f,0.f,0.f,0.f}}};
#pragma unroll
      for (int kk = 0; kk < 8; ++kk) {
        half8 af = *(const half8*)&A2s[((kk * 4 + lq) * 16 + l15) * 8];
        acc[kk & 1][0] = __builtin_amdgcn_mfma_f32_16x16x32_f16(W3r[kk * 2    ], af, acc[kk & 1][0], 0, 0, 0);
        acc[kk & 1][1] = __builtin_amdgcn_mfma_f32_16x16x32_f16(W3r[kk * 2 + 1], af, acc[kk & 1][1], 0, 0, 0);
      }
#pragma unroll
      for (int nt = 0; nt < 2; ++nt) {
        f32x4 s = acc[0][nt] + acc[1][nt] + bias3v[nt];
        short4v h4;
#pragma unroll
        for (int r4 = 0; r4 < 4; ++r4) h4[r4] = (short)f2h(ftanh(s[r4]));
        hv4[nt] = h4;
        *(short4v*)&A0s[((colb[nt] >> 3) * 16 + l15) * 8 + (colb[nt] & 7)] = h4;
      }
    }
    __syncthreads();
  }
  {                                                   // store final state (index nsteps)
    const int m = A.nsteps;
#pragma unroll
    for (int nt = 0; nt < 2; ++nt)
      *(short4v*)&statesb[((size_t)(g * 16 + l15) * MAXST + m) * HID + colb[nt]] = hv4[nt];
  }
}

// ---------------------------------------------------------------- fused batched MLP (fp16 MFMA)
// R11: 64-row blocks (512 x 256 thr) at 4 BLOCKS/CU. LDS = exactly 40 KB
// (32 KB act + 2x4 KB staging) -> 4 x 40 = 160 KB = full LDS; launch_bounds
// (256,4) pins the 128-VGPR budget (acc[4][4]=64, biases transient -> fits).
// vs r4 (32-row, 1024 blocks): same 16 waves/CU but HALF the W-frag L2
// re-stream (606 -> 303 MB, ~17.5 -> ~8.8us L2 floor). r5 showed this body
// is correct and =r4 at 3 blocks/CU; the 4th block/CU is the new bit.
__global__ __launch_bounds__(256, 4) void fused_kernel(
    const unsigned short* __restrict__ statesb, const float* __restrict__ logsig,
    const unsigned short* __restrict__ W1f, const unsigned short* __restrict__ W2f,
    const unsigned short* __restrict__ W3f, const unsigned short* __restrict__ Wlf,
    const float* __restrict__ b1, const float* __restrict__ b2, const float* __restrict__ b3,
    float* __restrict__ out, FuseArgs F)
{
  __shared__ __align__(16) unsigned short act[32 * 64 * 8];     // 32 KB, chunk-8 [col>>3][row][col&7]
  __shared__ __align__(16) unsigned short atile[2][4 * 64 * 8]; // 2 x 4 KB
  const int tid = threadIdx.x, b = blockIdx.x;
  const int lane = tid & 63, w = tid >> 6;
  const int l15 = lane & 15, lq = lane >> 4;

  f32x4 acc[4][4];
#pragma unroll
  for (int a = 0; a < 4; ++a)
#pragma unroll
    for (int t = 0; t < 4; ++t) acc[a][t] = (f32x4){0.f, 0.f, 0.f, 0.f};

  // ---- L1: K=416, A staged per-kk (dbuf, 1 barrier/kk), W-frags from L2
  const int lr = tid >> 2, lcc = (tid & 3) * 8;       // staging row / col-in-ktile
  short8 pk;
  auto loadA = [&](int kk) {
    int col = kk * 32 + lcc;
    if (col < HID) {
      pk = *(const short8*)(statesb + ((size_t)b * MAXST + F.sidx[lr]) * HID + col);
    } else {
      const float* sp = logsig + ((size_t)b * WIN + lr) * LSIG + (col - HID); // tail reads past 136 benign (W pad=0)
      float4 v0 = ((const float4*)sp)[0];
      float4 v1 = ((const float4*)sp)[1];
      short8 q;
      q[0] = (short)f2h(v0.x); q[1] = (short)f2h(v0.y); q[2] = (short)f2h(v0.z); q[3] = (short)f2h(v0.w);
      q[4] = (short)f2h(v1.x); q[5] = (short)f2h(v1.y); q[6] = (short)f2h(v1.z); q[7] = (short)f2h(v1.w);
      pk = q;
    }
  };
  loadA(0);
  for (int kk = 0; kk < 13; ++kk) {
    unsigned short* buf = &atile[kk & 1][0];
    *(short8*)&buf[((lcc >> 3) * 64 + lr) * 8] = pk;
    __syncthreads();
    if (kk + 1 < 13) loadA(kk + 1);           // issue early; hides under MFMAs
    half8 bfr[4];
#pragma unroll
    for (int t = 0; t < 4; ++t)
      bfr[t] = *(const half8*)(W1f + ((size_t)(kk * 16 + w * 4 + t) * 64 + lane) * 8);
#pragma unroll
    for (int a = 0; a < 4; ++a) {
      half8 af = *(const half8*)&buf[(lq * 64 + a * 16 + l15) * 8];
#pragma unroll
      for (int t = 0; t < 4; ++t)
        acc[a][t] = __builtin_amdgcn_mfma_f32_16x16x32_f16(bfr[t], af, acc[a][t], 0, 0, 0);
    }
  }
#pragma unroll
  for (int t = 0; t < 4; ++t) {                       // L1 epilogue: relu+b1 -> act
    const int col0 = w * 64 + t * 16 + lq * 4;
    f32x4 bb = *(const f32x4*)(b1 + col0);
#pragma unroll
    for (int a = 0; a < 4; ++a) {
      const int row = a * 16 + l15;
      short4v h4;
#pragma unroll
      for (int r4 = 0; r4 < 4; ++r4) h4[r4] = (short)f2h(fmaxf(acc[a][t][r4] + bb[r4], 0.f));
      *(short4v*)&act[((col0 >> 3) * 64 + row) * 8 + (col0 & 7)] = h4;
    }
  }
  __syncthreads();

  // ---- generic K=256 layer: A from act LDS (in-place reuse), W-frags from L2
  auto layer = [&](const unsigned short* Wf) {
#pragma unroll
    for (int a = 0; a < 4; ++a)
#pragma unroll
      for (int t = 0; t < 4; ++t) acc[a][t] = (f32x4){0.f, 0.f, 0.f, 0.f};
    for (int kk = 0; kk < 8; ++kk) {
      half8 bfr[4];
#pragma unroll
      for (int t = 0; t < 4; ++t)
        bfr[t] = *(const half8*)(Wf + ((size_t)(kk * 16 + w * 4 + t) * 64 + lane) * 8);
#pragma unroll
      for (int a = 0; a < 4; ++a) {
        half8 af = *(const half8*)&act[((kk * 4 + lq) * 64 + a * 16 + l15) * 8];
#pragma unroll
        for (int t = 0; t < 4; ++t)
          acc[a][t] = __builtin_amdgcn_mfma_f32_16x16x32_f16(bfr[t], af, acc[a][t], 0, 0, 0);
      }
    }
  };

  layer(W2f);                                         // L2 -> relu -> act (in place)
  __syncthreads();                                    // all act reads done
#pragma unroll
  for (int t = 0; t < 4; ++t) {
    const int col0 = w * 64 + t * 16 + lq * 4;
    f32x4 bb = *(const f32x4*)(b2 + col0);
#pragma unroll
    for (int a = 0; a < 4; ++a) {
      const int row = a * 16 + l15;
      short4v h4;
#pragma unroll
      for (int r4 = 0; r4 < 4; ++r4) h4[r4] = (short)f2h(fmaxf(acc[a][t][r4] + bb[r4], 0.f));
      *(short4v*)&act[((col0 >> 3) * 64 + row) * 8 + (col0 & 7)] = h4;
    }
  }
  __syncthreads();

  layer(W3f);                                         // L3 -> tanh -> act (in place)
  __syncthreads();
#pragma unroll
  for (int t = 0; t < 4; ++t) {
    const int col0 = w * 64 + t * 16 + lq * 4;
    f32x4 bb = *(const f32x4*)(b3 + col0);
#pragma unroll
    for (int a = 0; a < 4; ++a) {
      const int row = a * 16 + l15;
      short4v h4;
#pragma unroll
      for (int r4 = 0; r4 < 4; ++r4) h4[r4] = (short)f2h(ftanh(acc[a][t][r4] + bb[r4]));
      *(short4v*)&act[((col0 >> 3) * 64 + row) * 8 + (col0 & 7)] = h4;
    }
  }
  __syncthreads();

  layer(Wlf);                                         // L4 -> fp32 out (float4 stores)
#pragma unroll
  for (int t = 0; t < 4; ++t) {
    const int col0 = w * 64 + t * 16 + lq * 4;
#pragma unroll
    for (int a = 0; a < 4; ++a) {
      const int ks = a * 16 + l15;
      *(f32x4*)&out[((size_t)b * WIN + ks) * HID + col0] = acc[a][t];
    }
  }
}

// ---------------------------------------------------------------- host schedule
static void build_sched(SchedArgs& P, CombPArgs& CB, ChainArgs& CH, FuseArgs& FU) {
  double tb[SLEN], tt[WIN], tu[NWIN];
  const double s999 = 1.0 / (double)(SLEN - 1);
  const double s63  = 1.0 / (double)(WIN - 1);
  for (int i = 0; i < SLEN; ++i) tb[i] = (double)i * s999;
  tb[SLEN - 1] = 1.0;
  for (int k = 0; k < WIN; ++k) tt[k] = (double)k * s63;
  tt[WIN - 1] = 1.0;
  for (int j = 0; j < NWIN; ++j) tu[j] = tb[50 * j];

  int t_idx[WIN - 1], u_for_t[WIN - 1];
  for (int k = 1; k < WIN; ++k) {
    int ii = 0;
    for (int q = 0; q < SLEN; ++q) if (tb[q] <= tt[k]) ii = q;
    t_idx[k - 1] = ii;
    int jj = 0;
    for (int q = 0; q < NWIN; ++q) if (tu[q] <= tt[k]) jj = q;
    u_for_t[k - 1] = jj;
  }
  for (int t = 0; t < SLEN - 1; ++t) P.snapk[t] = 0;
  for (int m = 1; m < WIN; ++m) P.snapk[t_idx[m - 1] - 1] = (short)m;

  for (int m = 0; m < WIN; ++m) { CB.winofm[m] = 0; CB.zl[m] = 0; CB.sstep[m] = 255; }
  for (int m = 1; m < WIN; ++m) {
    int p = t_idx[m - 1];
    CB.winofm[m] = (unsigned char)((p - 1) / 50);
    CB.zl[m] = (p % 50 == 0) ? 1 : 0;
  }

  double qt[32]; int nq = 0, last = -1;
  for (int m = 0; m < WIN - 1; ++m) {
    const int iu = u_for_t[m];
    if (iu != last) { qt[nq++] = tu[iu]; last = iu; }
  }
  qt[nq++] = tt[WIN - 1];
  int upd[WIN]; int qh = 0;
  for (int i = 0; i < WIN; ++i) {
    upd[i] = 0;
    if (qh < nq && tt[i] >= qt[qh]) { qh++; upd[i] = 1; }
  }
  int nU = 0;
  for (int k = 0; k < WIN; ++k) if (upd[k]) { if (nU < 32) CH.kU[nU] = (unsigned char)k; ++nU; }
  int cnt = 0;
  for (int k = 0; k < WIN; ++k) { FU.sidx[k] = (unsigned char)cnt; if (upd[k]) ++cnt; }
  CH.nsteps = FU.sidx[WIN - 1];
  for (int s = 0; s < nU && s < 32; ++s)
    if (s < PSTEP) CB.sstep[CH.kU[s]] = (unsigned char)s;
}

extern "C" void kernel_launch(void* const* d_in, const int* in_sizes, int n_in,
                              void* d_out, int out_size, void* d_ws, size_t ws_size,
                              hipStream_t stream) {
  const float* z  = (const float*)d_in[0];
  const float* W1 = (const float*)d_in[1];
  const float* b1 = (const float*)d_in[2];
  const float* W2 = (const float*)d_in[3];
  const float* b2 = (const float*)d_in[4];
  const float* W3 = (const float*)d_in[5];
  const float* b3 = (const float*)d_in[6];
  const float* Wl = (const float*)d_in[7];

  char* ws = (char*)d_ws;
  float* logsig = (float*)(ws);                                         // 17.83 MB
  size_t o = (size_t)B_SZ * WIN * LSIG * 4;
  float* dxwin            = (float*)(ws + o); o += (size_t)B_SZ * NWIN * DD * 4;
  unsigned short* statesb = (unsigned short*)(ws + o); o += (size_t)B_SZ * MAXST * HID * 2;
  unsigned short* W1f     = (unsigned short*)(ws + o); o += (size_t)W1FN * 2;
  unsigned short* W2f     = (unsigned short*)(ws + o); o += (size_t)WFN * 2;
  unsigned short* W3f     = (unsigned short*)(ws + o); o += (size_t)WFN * 2;
  unsigned short* Wlf     = (unsigned short*)(ws + o); o += (size_t)WFN * 2;
  float* partial          = (float*)(ws + o); o += (size_t)32 * PSTEP * 16 * HID * 4; // 11.0 MB

  SchedArgs P; CombPArgs CB; ChainArgs CH; FuseArgs FU;
  build_sched(P, CB, CH, FU);

  prep_kernel<<<dim3(NWIN + 3, B_SZ), 128, 0, stream>>>(
      z, W1, W2, W3, Wl, logsig, dxwin, W1f, W2f, W3f, Wlf, P);
  combp_kernel<<<dim3(WIN, 32), 256, 0, stream>>>(logsig, dxwin, W1f, b1, partial, CB);
  chain_kernel<<<32, 512, 0, stream>>>(partial, W1f, W2f, W3f, b2, b3, statesb, CH);
  fused_kernel<<<512, 256, 0, stream>>>(statesb, logsig, W1f, W2f, W3f, Wlf,
                                        b1, b2, b3, (float*)d_out, FU);
}

// Round 12
// 218.437 us; speedup vs baseline: 1.0162x; 1.0162x over previous
//
#include <hip/hip_runtime.h>
#include <hip/hip_bf16.h>
#include <cmath>
#include <cstring>

#define B_SZ   512
#define SLEN   1000
#define DD     16
#define HID    256
#define WIN    64
#define PAIRS  120
#define LSIG   136
#define NWIN   20
#define MAXST  21
#define K1P    416     // layer-1 K padded to x32
#define W1FN   (13 * 16 * 64 * 8)   // 106496 elems
#define WFN    (8 * 16 * 64 * 8)    // 65536 elems (W2/W3/Wl)
#define PSTEP  21      // partial buffer step slots (nsteps <= 20)

using short8  = __attribute__((ext_vector_type(8))) short;
using short4v = __attribute__((ext_vector_type(4))) short;
using half8   = __attribute__((ext_vector_type(8))) _Float16;
using f32x4   = __attribute__((ext_vector_type(4))) float;

struct SchedArgs { short snapk[SLEN - 1]; };
struct CombPArgs { unsigned char winofm[WIN]; unsigned char zl[WIN]; unsigned char sstep[WIN]; };
struct ChainArgs { int nsteps; unsigned char kU[32]; };
struct FuseArgs  { unsigned char sidx[WIN]; };

__device__ __forceinline__ unsigned short f2h(float x) {
  _Float16 h = (_Float16)x;
  return __builtin_bit_cast(unsigned short, h);
}
__device__ __forceinline__ float ftanh(float x) {   // clamped; |err|~1e-6
  float t = fminf(fmaxf(2.f * x, -30.f), 30.f);
  float e = __expf(t);
  return (e - 1.f) / (e + 1.f);
}

// ---------------------------------------------------------------- prep: win scan + weight frag convert
// grid (NWIN+3, B_SZ) x 128. Blocks w<NWIN: per-window Levy scan. Else: convert
// W1/W2/W3/Wl -> fp16 MFMA B-frag layout:
//   Wf[(kk*16+nsub)*64+lane][j] = W[nsub*16+(lane&15)][kk*32+(lane>>4)*8+j]
__global__ __launch_bounds__(128) void prep_kernel(
    const float* __restrict__ z,
    const float* __restrict__ W1, const float* __restrict__ W2,
    const float* __restrict__ W3, const float* __restrict__ Wl,
    float* __restrict__ logsig, float* __restrict__ dxwin,
    unsigned short* __restrict__ W1f, unsigned short* __restrict__ W2f,
    unsigned short* __restrict__ W3f, unsigned short* __restrict__ Wlf,
    SchedArgs A)
{
  const int w = blockIdx.x, b = blockIdx.y, tid = threadIdx.x;
  if (w >= NWIN) {                                   // ---- weight conversion
    const int slot = ((w - NWIN) * B_SZ + b) * 128 + tid;   // 196608 slots
    for (int e = slot; e < W1FN + 3 * WFN; e += 3 * B_SZ * 128) {
      if (e < W1FN) {
        int f = e;
        int j = f & 7, l15 = (f >> 3) & 15, lq = (f >> 7) & 3, nsub = (f >> 9) & 15, kk = f >> 13;
        int row = nsub * 16 + l15, col = kk * 32 + lq * 8 + j;
        float v = (col < HID + LSIG) ? W1[(size_t)row * (HID + LSIG) + col] : 0.f;
        W1f[f] = f2h(v);
      } else {
        int e2 = e - W1FN;
        int which = e2 >> 16, f = e2 & 65535;
        int j = f & 7, l15 = (f >> 3) & 15, lq = (f >> 7) & 3, nsub = (f >> 9) & 15, kk = (f >> 13) & 7;
        int row = nsub * 16 + l15, col = kk * 32 + lq * 8 + j;
        const float* src = which == 0 ? W2 : which == 1 ? W3 : Wl;
        unsigned short* dst = which == 0 ? W2f : which == 1 ? W3f : Wlf;
        dst[f] = f2h(src[(size_t)row * HID + col]);
      }
    }
    return;
  }
  // ---- per-window Levy scan (dtsqrt inlined)
  __shared__ float zs[50][16];
  const int ns = (w == NWIN - 1) ? 49 : 50;
  const float* src = z + ((size_t)b * SLEN + 50 * w + 1) * DD;
  const double s999 = 1.0 / (double)(SLEN - 1);
  for (int c = tid; c < ns * 4; c += 128) {
    float4 v = ((const float4*)src)[c];
    int t = 50 * w + (c >> 2);
    double a = (t + 1 == SLEN - 1) ? 1.0 : (double)(t + 1) * s999;
    float s = sqrtf((float)(a - (double)t * s999));
    v.x *= s; v.y *= s; v.z *= s; v.w *= s;
    ((float4*)&zs[0][0])[c] = v;
  }
  int pi = 0, pj = 0;
  if (tid < PAIRS) { int rem = tid, i = 0; while (rem >= DD - 1 - i) { rem -= DD - 1 - i; ++i; } pi = i; pj = i + 1 + rem; }
  __syncthreads();
  float Yi = 0.f, Yj = 0.f, LL = 0.f, Yd = 0.f;
  const int base_t = 50 * w;
  for (int u = 0; u < ns; ++u) {
    const float di = zs[u][pi], dj = zs[u][pj];
    LL = fmaf(Yi, dj, LL); LL = fmaf(-Yj, di, LL);
    Yi += di; Yj += dj;
    if (tid < DD) Yd += zs[u][tid];
    const int m = A.snapk[base_t + u];
    if (m) {
      float* dst = logsig + ((size_t)b * WIN + m) * LSIG;
      if (tid < DD)    dst[tid]      = Yd;
      if (tid < PAIRS) dst[DD + tid] = LL;
    }
  }
  if (tid < DD) dxwin[((size_t)b * NWIN + w) * DD + tid] = Yd;
}

// ---------------------------------------------------------------- combine + logsig partial (merged)
// grid (WIN, 32) x 256. Block (k, g): finalize logsig rows for 16 batches
// (b = 16g..16g+15) at window k (level-1 add + Levy adjust), then -- if k is
// an update step (sstep[k]!=255) -- compute the chain's L1 partial
// partial[g][s][row][col] = (W1s . logsig)[row][col] + b1[col] straight from
// LDS with swapped-operand MFMA (D[feature][batch]: lane&15 = batch row, each
// lane holds 4 consecutive out-cols -> row-major float4 store).
// NOTE (r9 lesson): do NOT merge this lean kernel with the register-fat
// chain -- one kernel = one register allocation; producers inherit the fat
// footprint and occupancy collapses (measured 5x regression).
__global__ __launch_bounds__(256) void combp_kernel(
    float* __restrict__ logsig, const float* __restrict__ dxwin,
    const unsigned short* __restrict__ W1f, const float* __restrict__ b1,
    float* __restrict__ partial, CombPArgs A)
{
  __shared__ float Xs[16][16], Yt[16][16];
  __shared__ __align__(16) unsigned short As[20 * 16 * 8];   // 160 cols, chunk-8
  const int k = blockIdx.x, g = blockIdx.y, tid = threadIdx.x;
  const int w = A.winofm[k], zl = A.zl[k], ss = A.sstep[k];
  for (int c = tid; c < 3 * 16 * 8; c += 256) As[17 * 16 * 8 + c] = 0;  // zero pad cols 136..159
  {                                                   // ---- level-1 (tid = bi*16+col)
    const int bi = tid >> 4, col = tid & 15;
    const size_t b = (size_t)(g * 16 + bi);
    float acc = 0.f;
    for (int ww = 0; ww < w; ++ww) acc += dxwin[(b * NWIN + ww) * DD + col];
    float y = (k == 0) ? 0.f : logsig[(b * WIN + k) * LSIG + col];
    float fin = (k == 0) ? 0.f : acc + y;
    Xs[bi][col] = acc; Yt[bi][col] = y;
    logsig[(b * WIN + k) * LSIG + col] = fin;
    As[((col >> 3) * 16 + bi) * 8 + (col & 7)] = f2h(fin);
  }
  __syncthreads();
  for (int idx = tid; idx < 16 * PAIRS; idx += 256) {  // ---- Levy pairs
    const int bi = idx / PAIRS, p = idx - bi * PAIRS;
    int rem = p, i = 0; while (rem >= DD - 1 - i) { rem -= DD - 1 - i; ++i; }
    const int pi = i, pj = i + 1 + rem;
    const size_t b = (size_t)(g * 16 + bi);
    float ll = (k == 0) ? 0.f : logsig[(b * WIN + k) * LSIG + DD + p];
    float fin = (k == 0 || zl) ? 0.f
              : 0.5f * (ll + Xs[bi][pi] * Yt[bi][pj] - Xs[bi][pj] * Yt[bi][pi]);
    logsig[(b * WIN + k) * LSIG + DD + p] = fin;
    const int c = DD + p;
    As[((c >> 3) * 16 + bi) * 8 + (c & 7)] = f2h(fin);
  }
  if (ss == 255) return;                               // uniform across block
  __syncthreads();
  const int lane = tid & 63, wv = tid >> 6;
  const int l15 = lane & 15, lq = lane >> 4;
  f32x4 acc4[4] = {{0,0,0,0},{0,0,0,0},{0,0,0,0},{0,0,0,0}};
#pragma unroll
  for (int kt = 0; kt < 5; ++kt) {
    half8 af = *(const half8*)&As[((kt * 4 + lq) * 16 + l15) * 8];
#pragma unroll
    for (int t = 0; t < 4; ++t) {
      half8 bfW = *(const half8*)(W1f + ((size_t)((8 + kt) * 16 + wv * 4 + t) * 64 + lane) * 8);
      acc4[t] = __builtin_amdgcn_mfma_f32_16x16x32_f16(bfW, af, acc4[t], 0, 0, 0);
    }
  }
#pragma unroll
  for (int t = 0; t < 4; ++t) {
    const int col0 = wv * 64 + t * 16 + lq * 4;
    f32x4 bb = *(const f32x4*)(b1 + col0);
    f32x4 r = acc4[t] + bb;
    *(f32x4*)&partial[(((size_t)g * PSTEP + ss) * 16 + l15) * HID + col0] = r;
  }
}

// ---------------------------------------------------------------- sequential state chain (fp16 MFMA)
// = r6 (proven 46.5us, 6x reproduced). 32 blocks x 512 thr (8 waves, 2/SIMD).
// Wave w owns cols [32w,32w+32). All weights (48 half8 frags) resident in the
// unified VGPR/AGPR file. SWAPPED-OPERAND MFMA: D cols = batch (lane&15),
// each lane holds 4 consecutive feature cols -> packed b64 LDS epilogues +
// 8B global state stores (deferred one step). 3 barriers/step.
// Latency-bound by the 20-step serial dependency; structural attacks all
// regressed (r5 fewer-waves -42%, r9 cross-kernel overlap -65%).
__global__ __attribute__((amdgpu_flat_work_group_size(512, 512)))
__attribute__((amdgpu_waves_per_eu(2, 2)))
void chain_kernel(
    const float* __restrict__ partial,
    const unsigned short* __restrict__ W1f, const unsigned short* __restrict__ W2f,
    const unsigned short* __restrict__ W3f,
    const float* __restrict__ b2, const float* __restrict__ b3,
    unsigned short* __restrict__ statesb, ChainArgs A)
{
  __shared__ __align__(16) unsigned short A0s[32 * 16 * 8];   // 8 KB (h, chunk-8)
  __shared__ __align__(16) unsigned short A1s[32 * 16 * 8];   // 8 KB
  __shared__ __align__(16) unsigned short A2s[32 * 16 * 8];   // 8 KB
  const int tid = threadIdx.x, g = blockIdx.x;
  const int lane = tid & 63, w = tid >> 6;
  const int l15 = lane & 15, lq = lane >> 4;

  for (int c = tid; c < 32 * 16 * 8; c += 512) A0s[c] = 0;
  for (int c = tid; c < 16 * HID / 4; c += 512) {             // state 0 = zeros (8B packed)
    int r = c >> 6, col = (c & 63) * 4;
    *(short4v*)&statesb[((size_t)(g * 16 + r) * MAXST + 0) * HID + col] = (short4v){0, 0, 0, 0};
  }

  // ---- all weight frags -> registers (once, resident across all steps)
  half8 W1r[16], W2r[16], W3r[16];
#pragma unroll
  for (int kk = 0; kk < 8; ++kk)
#pragma unroll
    for (int nt = 0; nt < 2; ++nt) {
      W1r[kk * 2 + nt] = *(const half8*)(W1f + ((size_t)(kk * 16 + w * 2 + nt) * 64 + lane) * 8);
      W2r[kk * 2 + nt] = *(const half8*)(W2f + ((size_t)(kk * 16 + w * 2 + nt) * 64 + lane) * 8);
      W3r[kk * 2 + nt] = *(const half8*)(W3f + ((size_t)(kk * 16 + w * 2 + nt) * 64 + lane) * 8);
    }

  // per-lane column base (4 consecutive cols) for each n-tile
  int colb[2];
  f32x4 bias2v[2], bias3v[2];
#pragma unroll
  for (int nt = 0; nt < 2; ++nt) {
    colb[nt] = w * 32 + nt * 16 + lq * 4;
    bias2v[nt] = *(const f32x4*)(b2 + colb[nt]);
    bias3v[nt] = *(const f32x4*)(b3 + colb[nt]);
  }

  // partial prefetch plumbing (row-major [step][row16][256], float4/lane)
  const float* pbase = partial + (size_t)g * PSTEP * 16 * HID;
  int poff[2];
#pragma unroll
  for (int nt = 0; nt < 2; ++nt) poff[nt] = l15 * HID + colb[nt];
  f32x4 pf[2];
  pf[0] = *(const f32x4*)(pbase + poff[0]);
  pf[1] = *(const f32x4*)(pbase + poff[1]);

  short4v hv4[2];                                     // deferred packed state stores
  __syncthreads();                                    // A0s zeros visible

  for (int m = 0; m < A.nsteps; ++m) {
    if (m > 0) {                                      // store state m (from step m-1), 8B packed
#pragma unroll
      for (int nt = 0; nt < 2; ++nt)
        *(short4v*)&statesb[((size_t)(g * 16 + l15) * MAXST + m) * HID + colb[nt]] = hv4[nt];
    }
    // ---- L1: K=256 (h part), acc seeded from partial (has W1s.logsig + b1)
    {
      f32x4 acc[2][2];
      acc[0][0] = pf[0]; acc[0][1] = pf[1];
      acc[1][0] = (f32x4){0.f,0.f,0.f,0.f}; acc[1][1] = (f32x4){0.f,0.f,0.f,0.f};
      if (m + 1 < A.nsteps) {                         // prefetch next step's partial
        const float* pp = pbase + (size_t)(m + 1) * 16 * HID;
        pf[0] = *(const f32x4*)(pp + poff[0]);
        pf[1] = *(const f32x4*)(pp + poff[1]);
      }
#pragma unroll
      for (int kk = 0; kk < 8; ++kk) {
        half8 af = *(const half8*)&A0s[((kk * 4 + lq) * 16 + l15) * 8];
        acc[kk & 1][0] = __builtin_amdgcn_mfma_f32_16x16x32_f16(W1r[kk * 2    ], af, acc[kk & 1][0], 0, 0, 0);
        acc[kk & 1][1] = __builtin_amdgcn_mfma_f32_16x16x32_f16(W1r[kk * 2 + 1], af, acc[kk & 1][1], 0, 0, 0);
      }
#pragma unroll
      for (int nt = 0; nt < 2; ++nt) {
        f32x4 s = acc[0][nt] + acc[1][nt];
        short4v h4;
#pragma unroll
        for (int r4 = 0; r4 < 4; ++r4) h4[r4] = (short)f2h(fmaxf(s[r4], 0.f));
        *(short4v*)&A1s[((colb[nt] >> 3) * 16 + l15) * 8 + (colb[nt] & 7)] = h4;
      }
    }
    __syncthreads();
    // ---- L2: K=256, W2 from registers
    {
      f32x4 acc[2][2] = {{{0.f,0.f,0.f,0.f},{0.f,0.f,0.f,0.f}},{{0.f,0.f,0.f,0.f},{0.f,0.f,0.f,0.f}}};
#pragma unroll
      for (int kk = 0; kk < 8; ++kk) {
        half8 af = *(const half8*)&A1s[((kk * 4 + lq) * 16 + l15) * 8];
        acc[kk & 1][0] = __builtin_amdgcn_mfma_f32_16x16x32_f16(W2r[kk * 2    ], af, acc[kk & 1][0], 0, 0, 0);
        acc[kk & 1][1] = __builtin_amdgcn_mfma_f32_16x16x32_f16(W2r[kk * 2 + 1], af, acc[kk & 1][1], 0, 0, 0);
      }
#pragma unroll
      for (int nt = 0; nt < 2; ++nt) {
        f32x4 s = acc[0][nt] + acc[1][nt] + bias2v[nt];
        short4v h4;
#pragma unroll
        for (int r4 = 0; r4 < 4; ++r4) h4[r4] = (short)f2h(fmaxf(s[r4], 0.f));
        *(short4v*)&A2s[((colb[nt] >> 3) * 16 + l15) * 8 + (colb[nt] & 7)] = h4;
      }
    }
    __syncthreads();
    // ---- L3: K=256, W3 from registers; fast tanh -> A0 state; global store deferred
    {
      f32x4 acc[2][2] = {{{0.f,0.f,0.f,0.f},{0.f,0.f,0.f,0.f}},{{0.f,0.f,0.f,0.f},{0.f,0.f,0.f,0.f}}};
#pragma unroll
      for (int kk = 0; kk < 8; ++kk) {
        half8 af = *(const half8*)&A2s[((kk * 4 + lq) * 16 + l15) * 8];
        acc[kk & 1][0] = __builtin_amdgcn_mfma_f32_16x16x32_f16(W3r[kk * 2    ], af, acc[kk & 1][0], 0, 0, 0);
        acc[kk & 1][1] = __builtin_amdgcn_mfma_f32_16x16x32_f16(W3r[kk * 2 + 1], af, acc[kk & 1][1], 0, 0, 0);
      }
#pragma unroll
      for (int nt = 0; nt < 2; ++nt) {
        f32x4 s = acc[0][nt] + acc[1][nt] + bias3v[nt];
        short4v h4;
#pragma unroll
        for (int r4 = 0; r4 < 4; ++r4) h4[r4] = (short)f2h(ftanh(s[r4]));
        hv4[nt] = h4;
        *(short4v*)&A0s[((colb[nt] >> 3) * 16 + l15) * 8 + (colb[nt] & 7)] = h4;
      }
    }
    __syncthreads();
  }
  {                                                   // store final state (index nsteps)
    const int m = A.nsteps;
#pragma unroll
    for (int nt = 0; nt < 2; ++nt)
      *(short4v*)&statesb[((size_t)(g * 16 + l15) * MAXST + m) * HID + colb[nt]] = hv4[nt];
  }
}

// ---------------------------------------------------------------- fused batched MLP (fp16 MFMA)
// = r4 config (best-measured: totals 218.0 r4 / 218.9 r10): grid 1024 x 256
// thr, 32 rows/block (half a batch row), acc[2][4], LDS 20 KB -> 4 blocks/CU,
// 16 waves/CU. Proven staging (dbuf, 1 barrier/kk), in-place act reuse.
// Plateau established: r5 (64-row,3/CU), r8 (128-row,2/CU), r11 (64-row,4/CU)
// all equal-or-worse; r7 (no-staging direct loads) spilled acc. Latency-
// structured, not L2-BW-bound.
__global__ __launch_bounds__(256, 4) void fused_kernel(
    const unsigned short* __restrict__ statesb, const float* __restrict__ logsig,
    const unsigned short* __restrict__ W1f, const unsigned short* __restrict__ W2f,
    const unsigned short* __restrict__ W3f, const unsigned short* __restrict__ Wlf,
    const float* __restrict__ b1, const float* __restrict__ b2, const float* __restrict__ b3,
    float* __restrict__ out, FuseArgs F)
{
  __shared__ __align__(16) unsigned short act[32 * 32 * 8];     // 16 KB, chunk-8 [col>>3][row][col&7]
  __shared__ __align__(16) unsigned short atile[2][4 * 32 * 8]; // 2 x 2 KB
  const int tid = threadIdx.x;
  const int b = blockIdx.x >> 1, half = blockIdx.x & 1;
  const int lane = tid & 63, w = tid >> 6;
  const int l15 = lane & 15, lq = lane >> 4;

  f32x4 acc[2][4];
#pragma unroll
  for (int a = 0; a < 2; ++a)
#pragma unroll
    for (int t = 0; t < 4; ++t) acc[a][t] = (f32x4){0.f, 0.f, 0.f, 0.f};

  // ---- L1: K=416, A staged per-kk (dbuf, 1 barrier/kk), W-frags from L2
  const int lr = tid >> 3, lcc = (tid & 7) * 4;       // staging row / col-in-ktile
  const int lks = half * 32 + lr;
  short4v pk;
  auto loadA = [&](int kk) {
    int col = kk * 32 + lcc;
    if (col < HID) {
      pk = *(const short4v*)(statesb + ((size_t)b * MAXST + F.sidx[lks]) * HID + col);
    } else {
      const float* sp = logsig + ((size_t)b * WIN + lks) * LSIG + (col - HID); // tail reads past 136 benign (W pad=0)
      float4 v = *(const float4*)sp;
      short4v q;
      q[0] = (short)f2h(v.x); q[1] = (short)f2h(v.y); q[2] = (short)f2h(v.z); q[3] = (short)f2h(v.w);
      pk = q;
    }
  };
  loadA(0);
  for (int kk = 0; kk < 13; ++kk) {
    unsigned short* buf = &atile[kk & 1][0];
    *(short4v*)&buf[((lcc >> 3) * 32 + lr) * 8 + (lcc & 7)] = pk;
    __syncthreads();
    if (kk + 1 < 13) loadA(kk + 1);           // issue early; hides under MFMAs
    half8 bfr[4];
#pragma unroll
    for (int t = 0; t < 4; ++t)
      bfr[t] = *(const half8*)(W1f + ((size_t)(kk * 16 + w * 4 + t) * 64 + lane) * 8);
#pragma unroll
    for (int a = 0; a < 2; ++a) {
      half8 af = *(const half8*)&buf[(lq * 32 + a * 16 + l15) * 8];
#pragma unroll
      for (int t = 0; t < 4; ++t)
        acc[a][t] = __builtin_amdgcn_mfma_f32_16x16x32_f16(bfr[t], af, acc[a][t], 0, 0, 0);
    }
  }
#pragma unroll
  for (int t = 0; t < 4; ++t) {                       // L1 epilogue: relu+b1 -> act
    const int col0 = w * 64 + t * 16 + lq * 4;
    f32x4 bb = *(const f32x4*)(b1 + col0);
#pragma unroll
    for (int a = 0; a < 2; ++a) {
      const int row = a * 16 + l15;
      short4v h4;
#pragma unroll
      for (int r4 = 0; r4 < 4; ++r4) h4[r4] = (short)f2h(fmaxf(acc[a][t][r4] + bb[r4], 0.f));
      *(short4v*)&act[((col0 >> 3) * 32 + row) * 8 + (col0 & 7)] = h4;
    }
  }
  __syncthreads();

  // ---- generic K=256 layer: A from act LDS (in-place reuse), W-frags from L2
  auto layer = [&](const unsigned short* Wf) {
#pragma unroll
    for (int a = 0; a < 2; ++a)
#pragma unroll
      for (int t = 0; t < 4; ++t) acc[a][t] = (f32x4){0.f, 0.f, 0.f, 0.f};
    for (int kk = 0; kk < 8; ++kk) {
      half8 bfr[4];
#pragma unroll
      for (int t = 0; t < 4; ++t)
        bfr[t] = *(const half8*)(Wf + ((size_t)(kk * 16 + w * 4 + t) * 64 + lane) * 8);
#pragma unroll
      for (int a = 0; a < 2; ++a) {
        half8 af = *(const half8*)&act[((kk * 4 + lq) * 32 + a * 16 + l15) * 8];
#pragma unroll
        for (int t = 0; t < 4; ++t)
          acc[a][t] = __builtin_amdgcn_mfma_f32_16x16x32_f16(bfr[t], af, acc[a][t], 0, 0, 0);
      }
    }
  };

  layer(W2f);                                         // L2 -> relu -> act (in place)
  __syncthreads();                                    // all act reads done
#pragma unroll
  for (int t = 0; t < 4; ++t) {
    const int col0 = w * 64 + t * 16 + lq * 4;
    f32x4 bb = *(const f32x4*)(b2 + col0);
#pragma unroll
    for (int a = 0; a < 2; ++a) {
      const int row = a * 16 + l15;
      short4v h4;
#pragma unroll
      for (int r4 = 0; r4 < 4; ++r4) h4[r4] = (short)f2h(fmaxf(acc[a][t][r4] + bb[r4], 0.f));
      *(short4v*)&act[((col0 >> 3) * 32 + row) * 8 + (col0 & 7)] = h4;
    }
  }
  __syncthreads();

  layer(W3f);                                         // L3 -> tanh -> act (in place)
  __syncthreads();
#pragma unroll
  for (int t = 0; t < 4; ++t) {
    const int col0 = w * 64 + t * 16 + lq * 4;
    f32x4 bb = *(const f32x4*)(b3 + col0);
#pragma unroll
    for (int a = 0; a < 2; ++a) {
      const int row = a * 16 + l15;
      short4v h4;
#pragma unroll
      for (int r4 = 0; r4 < 4; ++r4) h4[r4] = (short)f2h(ftanh(acc[a][t][r4] + bb[r4]));
      *(short4v*)&act[((col0 >> 3) * 32 + row) * 8 + (col0 & 7)] = h4;
    }
  }
  __syncthreads();

  layer(Wlf);                                         // L4 -> fp32 out (float4 stores)
#pragma unroll
  for (int t = 0; t < 4; ++t) {
    const int col0 = w * 64 + t * 16 + lq * 4;
#pragma unroll
    for (int a = 0; a < 2; ++a) {
      const int ks = half * 32 + a * 16 + l15;
      *(f32x4*)&out[((size_t)b * WIN + ks) * HID + col0] = acc[a][t];
    }
  }
}

// ---------------------------------------------------------------- host schedule
static void build_sched(SchedArgs& P, CombPArgs& CB, ChainArgs& CH, FuseArgs& FU) {
  double tb[SLEN], tt[WIN], tu[NWIN];
  const double s999 = 1.0 / (double)(SLEN - 1);
  const double s63  = 1.0 / (double)(WIN - 1);
  for (int i = 0; i < SLEN; ++i) tb[i] = (double)i * s999;
  tb[SLEN - 1] = 1.0;
  for (int k = 0; k < WIN; ++k) tt[k] = (double)k * s63;
  tt[WIN - 1] = 1.0;
  for (int j = 0; j < NWIN; ++j) tu[j] = tb[50 * j];

  int t_idx[WIN - 1], u_for_t[WIN - 1];
  for (int k = 1; k < WIN; ++k) {
    int ii = 0;
    for (int q = 0; q < SLEN; ++q) if (tb[q] <= tt[k]) ii = q;
    t_idx[k - 1] = ii;
    int jj = 0;
    for (int q = 0; q < NWIN; ++q) if (tu[q] <= tt[k]) jj = q;
    u_for_t[k - 1] = jj;
  }
  for (int t = 0; t < SLEN - 1; ++t) P.snapk[t] = 0;
  for (int m = 1; m < WIN; ++m) P.snapk[t_idx[m - 1] - 1] = (short)m;

  for (int m = 0; m < WIN; ++m) { CB.winofm[m] = 0; CB.zl[m] = 0; CB.sstep[m] = 255; }
  for (int m = 1; m < WIN; ++m) {
    int p = t_idx[m - 1];
    CB.winofm[m] = (unsigned char)((p - 1) / 50);
    CB.zl[m] = (p % 50 == 0) ? 1 : 0;
  }

  double qt[32]; int nq = 0, last = -1;
  for (int m = 0; m < WIN - 1; ++m) {
    const int iu = u_for_t[m];
    if (iu != last) { qt[nq++] = tu[iu]; last = iu; }
  }
  qt[nq++] = tt[WIN - 1];
  int upd[WIN]; int qh = 0;
  for (int i = 0; i < WIN; ++i) {
    upd[i] = 0;
    if (qh < nq && tt[i] >= qt[qh]) { qh++; upd[i] = 1; }
  }
  int nU = 0;
  for (int k = 0; k < WIN; ++k) if (upd[k]) { if (nU < 32) CH.kU[nU] = (unsigned char)k; ++nU; }
  int cnt = 0;
  for (int k = 0; k < WIN; ++k) { FU.sidx[k] = (unsigned char)cnt; if (upd[k]) ++cnt; }
  CH.nsteps = FU.sidx[WIN - 1];
  for (int s = 0; s < nU && s < 32; ++s)
    if (s < PSTEP) CB.sstep[CH.kU[s]] = (unsigned char)s;
}

extern "C" void kernel_launch(void* const* d_in, const int* in_sizes, int n_in,
                              void* d_out, int out_size, void* d_ws, size_t ws_size,
                              hipStream_t stream) {
  const float* z  = (const float*)d_in[0];
  const float* W1 = (const float*)d_in[1];
  const float* b1 = (const float*)d_in[2];
  const float* W2 = (const float*)d_in[3];
  const float* b2 = (const float*)d_in[4];
  const float* W3 = (const float*)d_in[5];
  const float* b3 = (const float*)d_in[6];
  const float* Wl = (const float*)d_in[7];

  char* ws = (char*)d_ws;
  float* logsig = (float*)(ws);                                         // 17.83 MB
  size_t o = (size_t)B_SZ * WIN * LSIG * 4;
  float* dxwin            = (float*)(ws + o); o += (size_t)B_SZ * NWIN * DD * 4;
  unsigned short* statesb = (unsigned short*)(ws + o); o += (size_t)B_SZ * MAXST * HID * 2;
  unsigned short* W1f     = (unsigned short*)(ws + o); o += (size_t)W1FN * 2;
  unsigned short* W2f     = (unsigned short*)(ws + o); o += (size_t)WFN * 2;
  unsigned short* W3f     = (unsigned short*)(ws + o); o += (size_t)WFN * 2;
  unsigned short* Wlf     = (unsigned short*)(ws + o); o += (size_t)WFN * 2;
  float* partial          = (float*)(ws + o); o += (size_t)32 * PSTEP * 16 * HID * 4; // 11.0 MB

  SchedArgs P; CombPArgs CB; ChainArgs CH; FuseArgs FU;
  build_sched(P, CB, CH, FU);

  prep_kernel<<<dim3(NWIN + 3, B_SZ), 128, 0, stream>>>(
      z, W1, W2, W3, Wl, logsig, dxwin, W1f, W2f, W3f, Wlf, P);
  combp_kernel<<<dim3(WIN, 32), 256, 0, stream>>>(logsig, dxwin, W1f, b1, partial, CB);
  chain_kernel<<<32, 512, 0, stream>>>(partial, W1f, W2f, W3f, b2, b3, statesb, CH);
  fused_kernel<<<1024, 256, 0, stream>>>(statesb, logsig, W1f, W2f, W3f, Wlf,
                                         b1, b2, b3, (float*)d_out, FU);
}